// Round 8
// baseline (10392.416 us; speedup 1.0000x reference)
//
#include <hip/hip_runtime.h>
#include <hip/hip_bf16.h>

typedef __attribute__((ext_vector_type(8))) short bf16x8;
typedef __attribute__((ext_vector_type(4))) float f32x4;
typedef __attribute__((ext_vector_type(4))) unsigned int u32x4;
typedef __attribute__((ext_vector_type(2))) unsigned int u32x2;
typedef unsigned int u32;
typedef unsigned long long u64;
typedef unsigned short u16;

__device__ __forceinline__ short f2bf(float f) {
  __hip_bfloat16 h = __float2bfloat16(f);
  return *reinterpret_cast<short*>(&h);
}
__device__ __forceinline__ float bf2f(u16 s) {
  __hip_bfloat16 h;
  *reinterpret_cast<u16*>(&h) = s;
  return __bfloat162float(h);
}
__device__ __forceinline__ float sigm(float x) { return 1.f / (1.f + __expf(-x)); }

// ---- MALL-coherent transport ----
__device__ __forceinline__ u32x4 ld128_sys(const void* p) {
  u32x4 r;
  asm volatile("global_load_dwordx4 %0, %1, off sc0 sc1"
               : "=v"(r) : "v"((u64)(uintptr_t)p) : "memory");
  return r;
}
__device__ __forceinline__ void st64_sys(void* p, u32x2 v) {
  asm volatile("global_store_dwordx2 %0, %1, off sc0 sc1"
               :: "v"((u64)(uintptr_t)p), "v"(v) : "memory");
}
__device__ __forceinline__ void vm_drain() {
  asm volatile("s_waitcnt vmcnt(0)" ::: "memory");
  __builtin_amdgcn_sched_barrier(0);
}
__device__ __forceinline__ u32 ld_flag(const u32* p) {
  return __hip_atomic_load(const_cast<u32*>(p), __ATOMIC_RELAXED, __HIP_MEMORY_SCOPE_AGENT);
}
__device__ __forceinline__ void st_flag(u32* p, u32 v) {
  __hip_atomic_store(p, v, __ATOMIC_RELAXED, __HIP_MEMORY_SCOPE_AGENT);
}
__device__ __forceinline__ bool par_ok(u32x4 v, u32 pm) {
  u32 z = ((v[0] ^ pm) | (v[1] ^ pm) | (v[2] ^ pm) | (v[3] ^ pm)) & 0x00010001u;
  return z == 0;
}

// ---------------- precompute kernels ----------------
__global__ void swz_generic(const float* __restrict__ src, short* __restrict__ dst,
                            int row_stride, int col_off, int nks, int nunits) {
  int uid = blockIdx.x * blockDim.x + threadIdx.x;
  if (uid >= nunits) return;
  int lane = uid & 63;
  int rem  = uid >> 6;
  int ks = rem % nks;
  int nf = rem / nks;
  int row = nf * 16 + (lane & 15);
  int k0  = col_off + ks * 32 + (lane >> 4) * 8;
  const float* s = src + (size_t)row * row_stride + k0;
  short v[8];
#pragma unroll
  for (int e = 0; e < 8; ++e) v[e] = f2bf(s[e]);
  *reinterpret_cast<int4*>(dst + (size_t)uid * 8) = *reinterpret_cast<int4*>(v);
}

__global__ void xpose_kernel(const int* __restrict__ x, int* __restrict__ xT) {
  int i = blockIdx.x * blockDim.x + threadIdx.x;   // 131072
  int b = i >> 10, t = i & 1023;
  xT[t * 128 + b] = x[i];
}

__global__ __launch_bounds__(512) void table_kernel(
    const float* __restrict__ emb, const short* __restrict__ Wx,
    const float* __restrict__ b0, float* __restrict__ table) {
  __shared__ __align__(16) char smem[65536];
  const int tid = threadIdx.x;
  const int m0 = blockIdx.x * 64;
  const int nt = blockIdx.y;
  for (int i = tid; i < 4096; i += 512) {
    int row = i >> 6, seg = i & 63;
    const float* sp = emb + (size_t)(m0 + row) * 512 + seg * 8;
    short v[8];
#pragma unroll
    for (int e = 0; e < 8; ++e) v[e] = f2bf(sp[e]);
    *reinterpret_cast<int4*>(smem + row * 1024 + ((seg * 16) ^ ((row & 7) << 4))) =
        *reinterpret_cast<int4*>(v);
  }
  __syncthreads();
  const int w = tid >> 6, lane = tid & 63, l15 = lane & 15, lq = lane >> 4;
  const int mg = (w >> 2) * 32, np = w & 3;
  const char* ap = smem + (mg + l15) * 1024;
  const int swz = (l15 & 7) << 4;
  const int nfbase = nt * 8 + np * 2;
  const short* bp0 = Wx + (size_t)nfbase * 8192 + lane * 8;
  const short* bp1 = bp0 + 8192;
  f32x4 acc[2][2] = {};
#pragma unroll 4
  for (int ks = 0; ks < 16; ++ks) {
    int kb = ks * 64 + lq * 16;
    bf16x8 a0 = *reinterpret_cast<const bf16x8*>(ap + (kb ^ swz));
    bf16x8 a1 = *reinterpret_cast<const bf16x8*>(ap + 16 * 1024 + (kb ^ swz));
    bf16x8 bv0 = *reinterpret_cast<const bf16x8*>(bp0 + ks * 512);
    bf16x8 bv1 = *reinterpret_cast<const bf16x8*>(bp1 + ks * 512);
    acc[0][0] = __builtin_amdgcn_mfma_f32_16x16x32_bf16(a0, bv0, acc[0][0], 0, 0, 0);
    acc[1][0] = __builtin_amdgcn_mfma_f32_16x16x32_bf16(a1, bv0, acc[1][0], 0, 0, 0);
    acc[0][1] = __builtin_amdgcn_mfma_f32_16x16x32_bf16(a0, bv1, acc[0][1], 0, 0, 0);
    acc[1][1] = __builtin_amdgcn_mfma_f32_16x16x32_bf16(a1, bv1, acc[1][1], 0, 0, 0);
  }
#pragma unroll
  for (int mf = 0; mf < 2; ++mf)
#pragma unroll
    for (int nfi = 0; nfi < 2; ++nfi)
#pragma unroll
      for (int r = 0; r < 4; ++r) {
        int ncol = nt * 128 + np * 32 + nfi * 16 + l15;
        int vrow = m0 + mg + mf * 16 + lq * 4 + r;
        table[(size_t)vrow * 2048 + ncol] = acc[mf][nfi][r] + b0[ncol];
      }
}

// ---------------- LSTM role ----------------
// Both layers: M_wg=16 rows (bg 0..7), N_wg=512 gate-cols = 128 h-cols (cs 0..3).
// L0: 32 WGs, K=512 (h-part; x via table). L1: 32 WGs, K=1024, h1-half MFMA first.
template<int L>
__device__ void lstm_role(char* smem, int bg, int cs, int tid,
    const short* __restrict__ Wsw, const float* __restrict__ table,
    const float* __restrict__ bias1, const int* __restrict__ xT,
    u16* __restrict__ h0ring, u16* __restrict__ h1ring, u32* __restrict__ FP)
{
  constexpr int NKS  = (L == 0) ? 16 : 32;
  constexpr int ROWB = (L == 0) ? 1024 : 2048;
  const int w = tid >> 6, lane = tid & 63, l15 = lane & 15, lq = lane >> 4;
  const int g = w >> 1, half = w & 1;
  const int m0 = bg * 16;
  const int myid = (L == 0) ? (32 + bg * 4 + cs) : (bg * 4 + cs);
  const int nfb = g * 32 + cs * 8 + half * 4;
  const short* bb0 = Wsw + (size_t)(nfb + 0) * (NKS * 512) + lane * 8;
  const short* bb1 = Wsw + (size_t)(nfb + 1) * (NKS * 512) + lane * 8;
  const short* bb2 = Wsw + (size_t)(nfb + 2) * (NKS * 512) + lane * 8;
  const short* bb3 = Wsw + (size_t)(nfb + 3) * (NKS * 512) + lane * 8;
  float* glf = reinterpret_cast<float*>(smem + 32768);   // [4][16][128] f32
  int* xids = reinterpret_cast<int*>(smem + 65536);
  const int swz = (l15 & 7) << 4;
  const int erow = tid >> 5, ecol0 = (tid & 31) * 4;
  const int ecp = (ecol0 + ((erow >> 2) * 8)) & 127;      // un-rotated glf col
  float c[4] = {0.f, 0.f, 0.f, 0.f};
  f32x4 breg[4];
  if (L == 1) {
#pragma unroll
    for (int gg = 0; gg < 4; ++gg)
      breg[gg] = *reinterpret_cast<const f32x4*>(bias1 + gg * 512 + cs * 128 + ecol0);
  }

  for (int t = 0; t < 1024; ++t) {
    // ---- backpressure (every 8 ticks; readers of my ring slice) ----
    if (((t & 7) == 0) && t >= 16 && w == 0) {
      const u32* a = nullptr;
      if (L == 0) {
        if (lane < 4)      a = &FP[(32 + bg * 4 + lane) * 4];   // L0 peers
        else if (lane < 8) a = &FP[(bg * 4 + lane - 4) * 4];    // L1 consumers
      } else {
        if (lane < 4)       a = &FP[(bg * 4 + lane) * 4];       // L1 peers
        else if (lane == 4) a = &FP[(64 + bg) * 4];             // proj
      }
      if (a) { u32 tgt = (u32)(t - 6); while (ld_flag(a) < tgt) __builtin_amdgcn_s_sleep(1); }
    }
    if (L == 0 && tid < 16) xids[tid] = xT[t * 128 + m0 + tid];
    __syncthreads();

    f32x4 acc0 = {}, acc1 = {}, acc2 = {}, acc3 = {};
    const char* ap = smem + (size_t)l15 * ROWB;

    if (L == 0) {
      // ---- stage h0(t-1): 16 rows x 512 K ----
      if (t > 0) {
        const u32 pm = (((t - 1) >> 4) & 1) ? 0x00010001u : 0u;
        const u16* s0 = h0ring + (size_t)((t + 15) & 15) * 65536 + (size_t)m0 * 512;
        u32x4 v[2];
        int rr_[2], sg_[2];
#pragma unroll
        for (int k = 0; k < 2; ++k) {
          int gidx = tid + k * 512;
          rr_[k] = gidx >> 6; sg_[k] = gidx & 63;
          v[k] = ld128_sys(s0 + rr_[k] * 512 + sg_[k] * 8);
        }
        int pend = 3;
        while (pend) {
          vm_drain();
          int np = 0;
#pragma unroll
          for (int k = 0; k < 2; ++k) if (pend & (1 << k)) {
            if (par_ok(v[k], pm))
              *reinterpret_cast<u32x4*>(smem + rr_[k] * 1024 + ((sg_[k] * 16) ^ ((rr_[k] & 7) << 4))) = v[k];
            else { np |= 1 << k; v[k] = ld128_sys(s0 + rr_[k] * 512 + sg_[k] * 8); }
          }
          pend = np;
        }
      } else {
        u32x4 z = {0, 0, 0, 0};
#pragma unroll
        for (int k = 0; k < 2; ++k) {
          int gidx = tid + k * 512;
          int rr = gidx >> 6, seg = gidx & 63;
          *reinterpret_cast<u32x4*>(smem + rr * 1024 + ((seg * 16) ^ ((rr & 7) << 4))) = z;
        }
      }
      __syncthreads();
      if (tid == 0) st_flag(&FP[myid * 4], (u32)(t + 1));
      // table prefetch (overlaps MFMA)
      const float* tp = table + (size_t)xids[erow] * 2048 + cs * 128 + ecol0;
      f32x4 tb0 = *reinterpret_cast<const f32x4*>(tp);
      f32x4 tb1 = *reinterpret_cast<const f32x4*>(tp + 512);
      f32x4 tb2 = *reinterpret_cast<const f32x4*>(tp + 1024);
      f32x4 tb3 = *reinterpret_cast<const f32x4*>(tp + 1536);
#pragma unroll 4
      for (int ks = 0; ks < 16; ++ks) {
        bf16x8 a = *reinterpret_cast<const bf16x8*>(ap + ((ks * 64 + lq * 16) ^ swz));
        bf16x8 b0 = *reinterpret_cast<const bf16x8*>(bb0 + ks * 512);
        bf16x8 b1 = *reinterpret_cast<const bf16x8*>(bb1 + ks * 512);
        bf16x8 b2 = *reinterpret_cast<const bf16x8*>(bb2 + ks * 512);
        bf16x8 b3 = *reinterpret_cast<const bf16x8*>(bb3 + ks * 512);
        acc0 = __builtin_amdgcn_mfma_f32_16x16x32_bf16(a, b0, acc0, 0, 0, 0);
        acc1 = __builtin_amdgcn_mfma_f32_16x16x32_bf16(a, b1, acc1, 0, 0, 0);
        acc2 = __builtin_amdgcn_mfma_f32_16x16x32_bf16(a, b2, acc2, 0, 0, 0);
        acc3 = __builtin_amdgcn_mfma_f32_16x16x32_bf16(a, b3, acc3, 0, 0, 0);
      }
      // exchange + elementwise below (common path) uses tb*
      {
        f32x4 accs[4] = {acc0, acc1, acc2, acc3};
#pragma unroll
        for (int i = 0; i < 4; ++i)
#pragma unroll
          for (int r = 0; r < 4; ++r) {
            int lrow = lq * 4 + r;
            int col = (half * 4 + i) * 16 + l15;
            glf[(g * 16 + lrow) * 128 + ((col + lq * 8) & 127)] = accs[i][r];
          }
      }
      __syncthreads();
      f32x4 vi = *reinterpret_cast<const f32x4*>(&glf[(0 * 16 + erow) * 128 + ecp]);
      f32x4 vf = *reinterpret_cast<const f32x4*>(&glf[(1 * 16 + erow) * 128 + ecp]);
      f32x4 vo = *reinterpret_cast<const f32x4*>(&glf[(2 * 16 + erow) * 128 + ecp]);
      f32x4 vg = *reinterpret_cast<const f32x4*>(&glf[(3 * 16 + erow) * 128 + ecp]);
      u32 par = (u32)((t >> 4) & 1);
      u32 pk0 = 0, pk1 = 0;
#pragma unroll
      for (int e = 0; e < 4; ++e) {
        float cc = sigm(vf[e] + tb1[e]) * c[e] + sigm(vi[e] + tb0[e]) * tanhf(vg[e] + tb3[e]);
        c[e] = cc;
        float hh = sigm(vo[e] + tb2[e]) * tanhf(cc);
        u32 hb = ((u32)(u16)f2bf(hh) & ~1u) | par;
        if (e == 0) pk0 = hb; else if (e == 1) pk0 |= hb << 16;
        else if (e == 2) pk1 = hb; else pk1 |= hb << 16;
      }
      u32x2 pv; pv[0] = pk0; pv[1] = pk1;
      st64_sys(h0ring + (size_t)(t & 15) * 65536 + (size_t)(m0 + erow) * 512 + cs * 128 + ecol0, pv);
    } else {
      // ---- L1: issue h1 (k=2,3) then h0 (k=0,1); compute h1-half while h0 in flight ----
      const u32 pm0 = ((t >> 4) & 1) ? 0x00010001u : 0u;
      const u32 pm1 = (((t - 1) >> 4) & 1) ? 0x00010001u : 0u;
      const u16* s0 = h0ring + (size_t)(t & 15) * 65536 + (size_t)m0 * 512;
      const u16* s1 = h1ring + (size_t)((t + 15) & 15) * 65536 + (size_t)m0 * 512;
      u32x4 v[4];
      int rr_[4], sg_[4];
#pragma unroll
      for (int k = 0; k < 4; ++k) {
        int gidx = tid + k * 512;
        rr_[k] = (gidx & 1023) >> 6; sg_[k] = gidx & 63;
      }
      if (t > 0) {
        v[2] = ld128_sys(s1 + rr_[2] * 512 + sg_[2] * 8);
        v[3] = ld128_sys(s1 + rr_[3] * 512 + sg_[3] * 8);
      }
      v[0] = ld128_sys(s0 + rr_[0] * 512 + sg_[0] * 8);
      v[1] = ld128_sys(s0 + rr_[1] * 512 + sg_[1] * 8);
      if (t > 0) {
        asm volatile("s_waitcnt vmcnt(2)" ::: "memory");
        __builtin_amdgcn_sched_barrier(0);
        int pend = 0;
#pragma unroll
        for (int k = 2; k < 4; ++k) {
          if (par_ok(v[k], pm1))
            *reinterpret_cast<u32x4*>(smem + rr_[k] * 2048 + ((1024 + sg_[k] * 16) ^ ((rr_[k] & 7) << 4))) = v[k];
          else { pend |= 1 << k; v[k] = ld128_sys(s1 + rr_[k] * 512 + sg_[k] * 8); }
        }
        while (pend) {
          vm_drain();
          int np = 0;
#pragma unroll
          for (int k = 2; k < 4; ++k) if (pend & (1 << k)) {
            if (par_ok(v[k], pm1))
              *reinterpret_cast<u32x4*>(smem + rr_[k] * 2048 + ((1024 + sg_[k] * 16) ^ ((rr_[k] & 7) << 4))) = v[k];
            else { np |= 1 << k; v[k] = ld128_sys(s1 + rr_[k] * 512 + sg_[k] * 8); }
          }
          pend = np;
        }
      } else {
        u32x4 z = {0, 0, 0, 0};
#pragma unroll
        for (int k = 2; k < 4; ++k)
          *reinterpret_cast<u32x4*>(smem + rr_[k] * 2048 + ((1024 + sg_[k] * 16) ^ ((rr_[k] & 7) << 4))) = z;
      }
      __syncthreads();
#pragma unroll 4
      for (int ks = 16; ks < 32; ++ks) {   // h1-half MFMAs; h0 loads in flight
        bf16x8 a = *reinterpret_cast<const bf16x8*>(ap + ((ks * 64 + lq * 16) ^ swz));
        bf16x8 b0 = *reinterpret_cast<const bf16x8*>(bb0 + ks * 512);
        bf16x8 b1 = *reinterpret_cast<const bf16x8*>(bb1 + ks * 512);
        bf16x8 b2 = *reinterpret_cast<const bf16x8*>(bb2 + ks * 512);
        bf16x8 b3 = *reinterpret_cast<const bf16x8*>(bb3 + ks * 512);
        acc0 = __builtin_amdgcn_mfma_f32_16x16x32_bf16(a, b0, acc0, 0, 0, 0);
        acc1 = __builtin_amdgcn_mfma_f32_16x16x32_bf16(a, b1, acc1, 0, 0, 0);
        acc2 = __builtin_amdgcn_mfma_f32_16x16x32_bf16(a, b2, acc2, 0, 0, 0);
        acc3 = __builtin_amdgcn_mfma_f32_16x16x32_bf16(a, b3, acc3, 0, 0, 0);
      }
      {
        int pend = 3;
        while (pend) {
          vm_drain();
          int np = 0;
#pragma unroll
          for (int k = 0; k < 2; ++k) if (pend & (1 << k)) {
            if (par_ok(v[k], pm0))
              *reinterpret_cast<u32x4*>(smem + rr_[k] * 2048 + ((sg_[k] * 16) ^ ((rr_[k] & 7) << 4))) = v[k];
            else { np |= 1 << k; v[k] = ld128_sys(s0 + rr_[k] * 512 + sg_[k] * 8); }
          }
          pend = np;
        }
      }
      __syncthreads();
      if (tid == 0) st_flag(&FP[myid * 4], (u32)(t + 1));
#pragma unroll 4
      for (int ks = 0; ks < 16; ++ks) {    // h0-half MFMAs
        bf16x8 a = *reinterpret_cast<const bf16x8*>(ap + ((ks * 64 + lq * 16) ^ swz));
        bf16x8 b0 = *reinterpret_cast<const bf16x8*>(bb0 + ks * 512);
        bf16x8 b1 = *reinterpret_cast<const bf16x8*>(bb1 + ks * 512);
        bf16x8 b2 = *reinterpret_cast<const bf16x8*>(bb2 + ks * 512);
        bf16x8 b3 = *reinterpret_cast<const bf16x8*>(bb3 + ks * 512);
        acc0 = __builtin_amdgcn_mfma_f32_16x16x32_bf16(a, b0, acc0, 0, 0, 0);
        acc1 = __builtin_amdgcn_mfma_f32_16x16x32_bf16(a, b1, acc1, 0, 0, 0);
        acc2 = __builtin_amdgcn_mfma_f32_16x16x32_bf16(a, b2, acc2, 0, 0, 0);
        acc3 = __builtin_amdgcn_mfma_f32_16x16x32_bf16(a, b3, acc3, 0, 0, 0);
      }
      {
        f32x4 accs[4] = {acc0, acc1, acc2, acc3};
#pragma unroll
        for (int i = 0; i < 4; ++i)
#pragma unroll
          for (int r = 0; r < 4; ++r) {
            int lrow = lq * 4 + r;
            int col = (half * 4 + i) * 16 + l15;
            glf[(g * 16 + lrow) * 128 + ((col + lq * 8) & 127)] = accs[i][r];
          }
      }
      __syncthreads();
      f32x4 vi = *reinterpret_cast<const f32x4*>(&glf[(0 * 16 + erow) * 128 + ecp]);
      f32x4 vf = *reinterpret_cast<const f32x4*>(&glf[(1 * 16 + erow) * 128 + ecp]);
      f32x4 vo = *reinterpret_cast<const f32x4*>(&glf[(2 * 16 + erow) * 128 + ecp]);
      f32x4 vg = *reinterpret_cast<const f32x4*>(&glf[(3 * 16 + erow) * 128 + ecp]);
      u32 par = (u32)((t >> 4) & 1);
      u32 pk0 = 0, pk1 = 0;
#pragma unroll
      for (int e = 0; e < 4; ++e) {
        float cc = sigm(vf[e] + breg[1][e]) * c[e] + sigm(vi[e] + breg[0][e]) * tanhf(vg[e] + breg[3][e]);
        c[e] = cc;
        float hh = sigm(vo[e] + breg[2][e]) * tanhf(cc);
        u32 hb = ((u32)(u16)f2bf(hh) & ~1u) | par;
        if (e == 0) pk0 = hb; else if (e == 1) pk0 |= hb << 16;
        else if (e == 2) pk1 = hb; else pk1 |= hb << 16;
      }
      u32x2 pv; pv[0] = pk0; pv[1] = pk1;
      st64_sys(h1ring + (size_t)(t & 15) * 65536 + (size_t)(m0 + erow) * 512 + cs * 128 + ecol0, pv);
    }
  }
  vm_drain();
}

// ---------------- projection role (LN + [16x256] K=512 GEMM) ----------------
__device__ void proj_role(char* smem, int bg, int tid,
    const u16* __restrict__ h1ring, u32* __restrict__ FP,
    const short* __restrict__ pWswz, const float* __restrict__ lng,
    const float* __restrict__ lnb, const float* __restrict__ pb,
    float* __restrict__ out)
{
  const int w = tid >> 6, lane = tid & 63, l15 = lane & 15, lq = lane >> 4;
  const int m0 = bg * 16;
  const short* bp0 = pWswz + (size_t)(w * 2) * 8192 + lane * 8;
  const short* bp1 = bp0 + 8192;
  const int swzrow = (l15 & 7) << 4;
  float pb0 = pb[(w * 2) * 16 + l15], pb1 = pb[(w * 2 + 1) * 16 + l15];

  for (int t = 0; t < 1024; ++t) {
    {
      const u32 pm = ((t >> 4) & 1) ? 0x00010001u : 0u;
      const u16* src = h1ring + (size_t)(t & 15) * 65536 + (size_t)m0 * 512;
      u32x4 v[2];
      int pend = 3;
#pragma unroll
      for (int k = 0; k < 2; ++k) {
        int gidx = tid + k * 512;
        int rr = gidx >> 6, seg = gidx & 63;
        v[k] = ld128_sys(src + rr * 512 + seg * 8);
      }
      while (pend) {
        vm_drain();
        int np = 0;
#pragma unroll
        for (int k = 0; k < 2; ++k) if (pend & (1 << k)) {
          int gidx = tid + k * 512;
          int rr = gidx >> 6, seg = gidx & 63;
          if (par_ok(v[k], pm))
            *reinterpret_cast<u32x4*>(smem + rr * 1024 + seg * 16) = v[k];
          else { np |= 1 << k; v[k] = ld128_sys(src + rr * 512 + seg * 8); }
        }
        pend = np;
      }
    }
    __syncthreads();
    if (tid == 0) st_flag(&FP[(64 + bg) * 4], (u32)(t + 1));
    {
      int row = tid >> 5, j = tid & 31;
      const u16* hr = reinterpret_cast<const u16*>(smem) + row * 512;
      float s1 = 0.f, s2 = 0.f;
#pragma unroll
      for (int kk = 0; kk < 16; ++kk) {
        float v = bf2f(hr[j + kk * 32]);
        s1 += v; s2 += v * v;
      }
#pragma unroll
      for (int d = 1; d < 32; d <<= 1) { s1 += __shfl_xor(s1, d, 32); s2 += __shfl_xor(s2, d, 32); }
      float mu = s1 * (1.f / 512.f);
      float rs = rsqrtf(s2 * (1.f / 512.f) - mu * mu + 1e-5f);
      char* zn = smem + 16384;
#pragma unroll
      for (int kk = 0; kk < 16; ++kk) {
        int kcol = j + kk * 32;
        float v = bf2f(hr[kcol]);
        float nv = (v - mu) * rs * lng[kcol] + lnb[kcol];
        *reinterpret_cast<short*>(zn + row * 1024 + ((kcol * 2) ^ ((row & 7) << 4))) = f2bf(nv);
      }
    }
    __syncthreads();
    const char* ap = smem + 16384 + (size_t)l15 * 1024;
    f32x4 acc[2][2] = {};
#pragma unroll 4
    for (int ks = 0; ks < 16; ++ks) {
      bf16x8 a = *reinterpret_cast<const bf16x8*>(ap + ((ks * 64 + lq * 16) ^ swzrow));
      bf16x8 b0 = *reinterpret_cast<const bf16x8*>(bp0 + ks * 512);
      bf16x8 b1 = *reinterpret_cast<const bf16x8*>(bp1 + ks * 512);
      acc[0][ks & 1] = __builtin_amdgcn_mfma_f32_16x16x32_bf16(a, b0, acc[0][ks & 1], 0, 0, 0);
      acc[1][ks & 1] = __builtin_amdgcn_mfma_f32_16x16x32_bf16(a, b1, acc[1][ks & 1], 0, 0, 0);
    }
#pragma unroll
    for (int nfi = 0; nfi < 2; ++nfi) {
      int vcol = (w * 2 + nfi) * 16 + l15;
      float pbv = nfi ? pb1 : pb0;
#pragma unroll
      for (int r = 0; r < 4; ++r) {
        float vv = acc[nfi][0][r] + acc[nfi][1][r] + pbv;
        out[(size_t)(m0 + lq * 4 + r) * 262144 + (size_t)t * 256 + vcol] = vv;
      }
    }
    __syncthreads();
  }
}

// Grid: 72 blocks. 0..31 = L1 (bg=bid>>2, cs=bid&3), 32..63 = L0, 64..71 = proj.
__global__ __launch_bounds__(512, 1) void persist_kernel(
    const short* __restrict__ W0h, const short* __restrict__ W1,
    const float* __restrict__ table, const float* __restrict__ bias1,
    const int* __restrict__ xT,
    u16* __restrict__ h0ring, u16* __restrict__ h1ring, u32* __restrict__ flags,
    const short* __restrict__ pWswz, const float* __restrict__ lng,
    const float* __restrict__ lnb, const float* __restrict__ pb, float* __restrict__ out)
{
  __shared__ __align__(16) char smem[65600];
  const int bid = blockIdx.x, tid = threadIdx.x;
  if (bid < 32) {
    lstm_role<1>(smem, bid >> 2, bid & 3, tid, W1, nullptr, bias1, xT,
                 h0ring, h1ring, flags);
  } else if (bid < 64) {
    int idx = bid - 32;
    lstm_role<0>(smem, idx >> 2, idx & 3, tid, W0h, table, nullptr, xT,
                 h0ring, h1ring, flags);
  } else {
    proj_role(smem, bid - 64, tid, h1ring, flags, pWswz, lng, lnb, pb, out);
  }
}

extern "C" void kernel_launch(void* const* d_in, const int* in_sizes, int n_in,
                              void* d_out, int out_size, void* d_ws, size_t ws_size,
                              hipStream_t stream) {
  const int*   x    = (const int*)d_in[0];
  const float* emb  = (const float*)d_in[1];
  const float* W    = (const float*)d_in[2];
  const float* bias = (const float*)d_in[3];
  const float* lng  = (const float*)d_in[4];
  const float* lnb  = (const float*)d_in[5];
  const float* pW   = (const float*)d_in[6];
  const float* pb   = (const float*)d_in[7];
  float* out = (float*)d_out;

  char* ws = (char*)d_ws;
  short* W0h   = (short*)(ws + 0);           // 2 MB
  short* W1sw  = (short*)(ws + 2097152);     // 4 MB
  short* pWsw  = (short*)(ws + 6291456);     // 256 KB
  float* table = (float*)(ws + 6815744);     // 2 MB
  int*   xT    = (int*)(ws + 8912896);       // 512 KB
  u32*   flags = (u32*)(ws + 9437184);       // 4 KB (prog)
  u16*   h0ring= (u16*)(ws + 9961472);       // 2 MB: 16 x [128][512] bf16 (parity LSB)
  u16*   h1ring= (u16*)(ws + 12058624);      // 2 MB
  short* W0x   = (short*)(ws + 14155776);    // 2 MB temp (table build)

  swz_generic<<<dim3(512), dim3(256), 0, stream>>>(W, W0h, 1024, 512, 16, 131072);
  swz_generic<<<dim3(1024), dim3(256), 0, stream>>>(W + 2048 * 1024, W1sw, 1024, 0, 32, 262144);
  swz_generic<<<dim3(64), dim3(256), 0, stream>>>(pW, pWsw, 512, 0, 16, 16384);
  xpose_kernel<<<dim3(512), dim3(256), 0, stream>>>(x, xT);
  swz_generic<<<dim3(512), dim3(256), 0, stream>>>(W, W0x, 1024, 0, 16, 131072);
  table_kernel<<<dim3(4, 16), dim3(512), 0, stream>>>(emb, W0x, bias, table);
  hipMemsetAsync(ws + 9437184, 0, 4096, stream);          // prog flags
  hipMemsetAsync(ws + 9961472, 0x01, 4194304, stream);    // rings: LSB=1 rejects first-epoch reads

  persist_kernel<<<dim3(72), dim3(512), 0, stream>>>(
      W0h, W1sw, table, bias + 2048, xT, h0ring, h1ring, flags,
      pWsw, lng, lnb, pb, out);
}

// Round 9
// 9880.712 us; speedup vs baseline: 1.0518x; 1.0518x over previous
//
#include <hip/hip_runtime.h>
#include <hip/hip_bf16.h>

typedef __attribute__((ext_vector_type(8))) short bf16x8;
typedef __attribute__((ext_vector_type(4))) float f32x4;
typedef __attribute__((ext_vector_type(4))) unsigned int u32x4;
typedef __attribute__((ext_vector_type(2))) unsigned int u32x2;
typedef unsigned int u32;
typedef unsigned long long u64;
typedef unsigned short u16;

__device__ __forceinline__ short f2bf(float f) {
  __hip_bfloat16 h = __float2bfloat16(f);
  return *reinterpret_cast<short*>(&h);
}
__device__ __forceinline__ float bf2f(u16 s) {
  __hip_bfloat16 h;
  *reinterpret_cast<u16*>(&h) = s;
  return __bfloat162float(h);
}
__device__ __forceinline__ float sigm(float x) { return 1.f / (1.f + __expf(-x)); }

// ---- transport ----
// local (intra-XCD L2): plain store, sc0 load (bypass CU vL1, served by XCD L2)
__device__ __forceinline__ u32x4 ld128_loc(const void* p) {
  u32x4 r;
  asm volatile("global_load_dwordx4 %0, %1, off sc0"
               : "=v"(r) : "v"((u64)(uintptr_t)p) : "memory");
  return r;
}
__device__ __forceinline__ void st64_loc(void* p, u32x2 v) {
  asm volatile("global_store_dwordx2 %0, %1, off"
               :: "v"((u64)(uintptr_t)p), "v"(v) : "memory");
}
// MALL-coherent (cross-XCD safe) — R7-proven
__device__ __forceinline__ u32x4 ld128_sys(const void* p) {
  u32x4 r;
  asm volatile("global_load_dwordx4 %0, %1, off sc0 sc1"
               : "=v"(r) : "v"((u64)(uintptr_t)p) : "memory");
  return r;
}
__device__ __forceinline__ void st64_sys(void* p, u32x2 v) {
  asm volatile("global_store_dwordx2 %0, %1, off sc0 sc1"
               :: "v"((u64)(uintptr_t)p), "v"(v) : "memory");
}
__device__ __forceinline__ void vm_drain() {
  asm volatile("s_waitcnt vmcnt(0)" ::: "memory");
  __builtin_amdgcn_sched_barrier(0);
}
__device__ __forceinline__ u32 ld_flag(const u32* p) {
  return __hip_atomic_load(const_cast<u32*>(p), __ATOMIC_RELAXED, __HIP_MEMORY_SCOPE_AGENT);
}
__device__ __forceinline__ void st_flag(u32* p, u32 v) {
  __hip_atomic_store(p, v, __ATOMIC_RELAXED, __HIP_MEMORY_SCOPE_AGENT);
}
__device__ __forceinline__ bool par_ok(u32x4 v, u32 pm) {
  u32 z = ((v[0] ^ pm) | (v[1] ^ pm) | (v[2] ^ pm) | (v[3] ^ pm)) & 0x00010001u;
  return z == 0;
}

// ---------------- precompute kernels ----------------
__global__ void swz_generic(const float* __restrict__ src, short* __restrict__ dst,
                            int row_stride, int col_off, int nks, int nunits) {
  int uid = blockIdx.x * blockDim.x + threadIdx.x;
  if (uid >= nunits) return;
  int lane = uid & 63;
  int rem  = uid >> 6;
  int ks = rem % nks;
  int nf = rem / nks;
  int row = nf * 16 + (lane & 15);
  int k0  = col_off + ks * 32 + (lane >> 4) * 8;
  const float* s = src + (size_t)row * row_stride + k0;
  short v[8];
#pragma unroll
  for (int e = 0; e < 8; ++e) v[e] = f2bf(s[e]);
  *reinterpret_cast<int4*>(dst + (size_t)uid * 8) = *reinterpret_cast<int4*>(v);
}

__global__ void xpose_kernel(const int* __restrict__ x, int* __restrict__ xT) {
  int i = blockIdx.x * blockDim.x + threadIdx.x;   // 131072
  int b = i >> 10, t = i & 1023;
  xT[t * 128 + b] = x[i];
}

__global__ __launch_bounds__(512) void table_kernel(
    const float* __restrict__ emb, const short* __restrict__ Wx,
    const float* __restrict__ b0, float* __restrict__ table) {
  __shared__ __align__(16) char smem[65536];
  const int tid = threadIdx.x;
  const int m0 = blockIdx.x * 64;
  const int nt = blockIdx.y;
  for (int i = tid; i < 4096; i += 512) {
    int row = i >> 6, seg = i & 63;
    const float* sp = emb + (size_t)(m0 + row) * 512 + seg * 8;
    short v[8];
#pragma unroll
    for (int e = 0; e < 8; ++e) v[e] = f2bf(sp[e]);
    *reinterpret_cast<int4*>(smem + row * 1024 + ((seg * 16) ^ ((row & 7) << 4))) =
        *reinterpret_cast<int4*>(v);
  }
  __syncthreads();
  const int w = tid >> 6, lane = tid & 63, l15 = lane & 15, lq = lane >> 4;
  const int mg = (w >> 2) * 32, np = w & 3;
  const char* ap = smem + (mg + l15) * 1024;
  const int swz = (l15 & 7) << 4;
  const int nfbase = nt * 8 + np * 2;
  const short* bp0 = Wx + (size_t)nfbase * 8192 + lane * 8;
  const short* bp1 = bp0 + 8192;
  f32x4 acc[2][2] = {};
#pragma unroll 4
  for (int ks = 0; ks < 16; ++ks) {
    int kb = ks * 64 + lq * 16;
    bf16x8 a0 = *reinterpret_cast<const bf16x8*>(ap + (kb ^ swz));
    bf16x8 a1 = *reinterpret_cast<const bf16x8*>(ap + 16 * 1024 + (kb ^ swz));
    bf16x8 bv0 = *reinterpret_cast<const bf16x8*>(bp0 + ks * 512);
    bf16x8 bv1 = *reinterpret_cast<const bf16x8*>(bp1 + ks * 512);
    acc[0][0] = __builtin_amdgcn_mfma_f32_16x16x32_bf16(a0, bv0, acc[0][0], 0, 0, 0);
    acc[1][0] = __builtin_amdgcn_mfma_f32_16x16x32_bf16(a1, bv0, acc[1][0], 0, 0, 0);
    acc[0][1] = __builtin_amdgcn_mfma_f32_16x16x32_bf16(a0, bv1, acc[0][1], 0, 0, 0);
    acc[1][1] = __builtin_amdgcn_mfma_f32_16x16x32_bf16(a1, bv1, acc[1][1], 0, 0, 0);
  }
#pragma unroll
  for (int mf = 0; mf < 2; ++mf)
#pragma unroll
    for (int nfi = 0; nfi < 2; ++nfi)
#pragma unroll
      for (int r = 0; r < 4; ++r) {
        int ncol = nt * 128 + np * 32 + nfi * 16 + l15;
        int vrow = m0 + mg + mf * 16 + lq * 4 + r;
        table[(size_t)vrow * 2048 + ncol] = acc[mf][nfi][r] + b0[ncol];
      }
}

// ---------------- LSTM role (R7 decomposition) ----------------
// L0: 8 cs-WGs/bg: NCOL=64 h-cols, K=512. L1: 16 cs-WGs/bg: NCOL=32, K=1024.
template<int L>
__device__ void lstm_role(char* smem, int bg, int cs, int tid,
    const short* __restrict__ Wsw, const float* __restrict__ table,
    const float* __restrict__ bias1, const int* __restrict__ xT,
    u16* __restrict__ h0loc, u16* __restrict__ h1loc,
    u16* __restrict__ h0mall, u16* __restrict__ h1mall, u32* __restrict__ FP)
{
  constexpr int NCOL = (L == 0) ? 64 : 32;
  constexpr int NKS  = (L == 0) ? 16 : 32;
  constexpr int ROWB = (L == 0) ? 1024 : 2048;
  const int w = tid >> 6, lane = tid & 63, l15 = lane & 15, lq = lane >> 4;
  const int g = w >> 1;
  const int m0 = bg * 16;
  const int myid = (L == 0) ? (128 + bg * 8 + cs) : (bg * 16 + cs);
  const int nf0 = g * 32 + cs * (NCOL / 16) + (w & 1) * ((L == 0) ? 2 : 1);
  const short* bb0 = Wsw + (size_t)nf0 * (NKS * 512) + lane * 8;
  const short* bb1 = (L == 0) ? bb0 + (size_t)(NKS * 512) : nullptr;
  float* glf = reinterpret_cast<float*>(smem + ((L == 0) ? 16384 : 32768));
  int* xids = reinterpret_cast<int*>(smem + ((L == 0) ? 32768 : 40960));
  const int swz = (l15 & 7) << 4;
  const bool ew = (L == 0) ? true : (tid < 256);
  const int erow = (L == 0) ? (tid >> 5) : (tid >> 4);
  const int ecp  = (L == 0) ? ((tid & 31) * 2) : ((tid & 15) * 2);
  const int esh  = ((erow >> 2) & 3) * 8;
  float c0 = 0.f, c1 = 0.f;
  float2 breg[4];
  if (L == 1 && ew) {
#pragma unroll
    for (int gg = 0; gg < 4; ++gg)
      breg[gg] = *reinterpret_cast<const float2*>(bias1 + gg * 512 + cs * 32 + ecp);
  }

  for (int t = 0; t < 1024; ++t) {
    // ---- backpressure (every 8 ticks, FP only) ----
    if (((t & 7) == 0) && t >= 16) {
      if (w == 0) {
        const u32* a = nullptr;
        if (L == 0) {
          if (lane < 16)      a = &FP[(bg * 16 + lane) * 4];
          else if (lane < 24) a = &FP[(128 + bg * 8 + lane - 16) * 4];
        } else {
          if (lane < 16)      a = &FP[(bg * 16 + lane) * 4];
          else if (lane == 16) a = &FP[(192 + bg) * 4];
        }
        if (a) { u32 tgt = (u32)(t - 6); while (ld_flag(a) < tgt) __builtin_amdgcn_s_sleep(1); }
      }
    }
    if (L == 0 && tid < 16) xids[tid] = xT[t * 128 + m0 + tid];
    __syncthreads();
    // ---- stage A: parity-validated retry (local L2 fast path, MALL fallback) ----
    if (L == 0) {
      const u32 pm = (((t - 1) >> 4) & 1) ? 0x00010001u : 0u;
      const size_t off = (size_t)((t + 15) & 15) * 65536 + (size_t)m0 * 512;
      const u16* sL = h0loc + off;
      const u16* sM = h0mall + off;
      u32x4 v[2];
      int rr_[2], sg_[2];
#pragma unroll
      for (int k = 0; k < 2; ++k) {
        int gidx = tid + k * 512;
        rr_[k] = gidx >> 6; sg_[k] = gidx & 63;
      }
      if (t > 0) {
#pragma unroll
        for (int k = 0; k < 2; ++k) v[k] = ld128_loc(sL + rr_[k] * 512 + sg_[k] * 8);
        int pend = 3, rnd = 0;
        while (pend) {
          vm_drain();
          int np = 0;
          const bool useM = (rnd >= 4) && (rnd & 1);
#pragma unroll
          for (int k = 0; k < 2; ++k) if (pend & (1 << k)) {
            if (par_ok(v[k], pm))
              *reinterpret_cast<u32x4*>(smem + rr_[k] * 1024 + ((sg_[k] * 16) ^ ((rr_[k] & 7) << 4))) = v[k];
            else {
              np |= 1 << k;
              v[k] = useM ? ld128_sys(sM + rr_[k] * 512 + sg_[k] * 8)
                          : ld128_loc(sL + rr_[k] * 512 + sg_[k] * 8);
            }
          }
          pend = np; ++rnd;
        }
      } else {
        u32x4 z = {0, 0, 0, 0};
#pragma unroll
        for (int k = 0; k < 2; ++k)
          *reinterpret_cast<u32x4*>(smem + rr_[k] * 1024 + ((sg_[k] * 16) ^ ((rr_[k] & 7) << 4))) = z;
      }
    } else {
      const u32 pm0 = ((t >> 4) & 1) ? 0x00010001u : 0u;          // h0 epoch t
      const u32 pm1 = (((t - 1) >> 4) & 1) ? 0x00010001u : 0u;    // h1 epoch t-1
      const size_t off0 = (size_t)(t & 15) * 65536 + (size_t)m0 * 512;
      const size_t off1 = (size_t)((t + 15) & 15) * 65536 + (size_t)m0 * 512;
      const u16* s0L = h0loc + off0;  const u16* s0M = h0mall + off0;
      const u16* s1L = h1loc + off1;  const u16* s1M = h1mall + off1;
      u32x4 v[4];
      int rr_[4], sg_[4];
#pragma unroll
      for (int k = 0; k < 4; ++k) {
        int gidx = tid + k * 512;
        rr_[k] = (gidx & 1023) >> 6; sg_[k] = gidx & 63;
      }
      // issue h1 (k=2,3) then h0 (k=0,1); validate h1 first (vmcnt(2))
      if (t > 0) {
        v[2] = ld128_loc(s1L + rr_[2] * 512 + sg_[2] * 8);
        v[3] = ld128_loc(s1L + rr_[3] * 512 + sg_[3] * 8);
      }
      v[0] = ld128_loc(s0L + rr_[0] * 512 + sg_[0] * 8);
      v[1] = ld128_loc(s0L + rr_[1] * 512 + sg_[1] * 8);
      if (t > 0) {
        asm volatile("s_waitcnt vmcnt(2)" ::: "memory");
        __builtin_amdgcn_sched_barrier(0);
        int pend = 0;
#pragma unroll
        for (int k = 2; k < 4; ++k) {
          if (par_ok(v[k], pm1))
            *reinterpret_cast<u32x4*>(smem + rr_[k] * 2048 + ((1024 + sg_[k] * 16) ^ ((rr_[k] & 7) << 4))) = v[k];
          else { pend |= 1 << k; v[k] = ld128_loc(s1L + rr_[k] * 512 + sg_[k] * 8); }
        }
        int rnd = 1;
        while (pend) {
          vm_drain();
          int np = 0;
          const bool useM = (rnd >= 4) && (rnd & 1);
#pragma unroll
          for (int k = 2; k < 4; ++k) if (pend & (1 << k)) {
            if (par_ok(v[k], pm1))
              *reinterpret_cast<u32x4*>(smem + rr_[k] * 2048 + ((1024 + sg_[k] * 16) ^ ((rr_[k] & 7) << 4))) = v[k];
            else {
              np |= 1 << k;
              v[k] = useM ? ld128_sys(s1M + rr_[k] * 512 + sg_[k] * 8)
                          : ld128_loc(s1L + rr_[k] * 512 + sg_[k] * 8);
            }
          }
          pend = np; ++rnd;
        }
      } else {
        u32x4 z = {0, 0, 0, 0};
#pragma unroll
        for (int k = 2; k < 4; ++k)
          *reinterpret_cast<u32x4*>(smem + rr_[k] * 2048 + ((1024 + sg_[k] * 16) ^ ((rr_[k] & 7) << 4))) = z;
      }
      {
        int pend = 3, rnd = 0;
        while (pend) {
          vm_drain();
          int np = 0;
          const bool useM = (rnd >= 4) && (rnd & 1);
#pragma unroll
          for (int k = 0; k < 2; ++k) if (pend & (1 << k)) {
            if (par_ok(v[k], pm0))
              *reinterpret_cast<u32x4*>(smem + rr_[k] * 2048 + ((sg_[k] * 16) ^ ((rr_[k] & 7) << 4))) = v[k];
            else {
              np |= 1 << k;
              v[k] = useM ? ld128_sys(s0M + rr_[k] * 512 + sg_[k] * 8)
                          : ld128_loc(s0L + rr_[k] * 512 + sg_[k] * 8);
            }
          }
          pend = np; ++rnd;
        }
      }
    }
    __syncthreads();
    if (tid == 0) st_flag(&FP[myid * 4], (u32)(t + 1));
    // ---- table prefetch (L0) ----
    float2 tb[4];
    if (L == 0) {
      const float* tp = table + (size_t)xids[erow] * 2048 + cs * 64 + ecp;
      tb[0] = *reinterpret_cast<const float2*>(tp);
      tb[1] = *reinterpret_cast<const float2*>(tp + 512);
      tb[2] = *reinterpret_cast<const float2*>(tp + 1024);
      tb[3] = *reinterpret_cast<const float2*>(tp + 1536);
    }
    // ---- MFMA ----
    const char* ap = smem + (size_t)l15 * ROWB;
    if (L == 0) {
      f32x4 acc[2][2] = {};
#pragma unroll 4
      for (int ks = 0; ks < NKS; ++ks) {
        bf16x8 a = *reinterpret_cast<const bf16x8*>(ap + ((ks * 64 + lq * 16) ^ swz));
        bf16x8 b0 = *reinterpret_cast<const bf16x8*>(bb0 + ks * 512);
        bf16x8 b1 = *reinterpret_cast<const bf16x8*>(bb1 + ks * 512);
        acc[0][ks & 1] = __builtin_amdgcn_mfma_f32_16x16x32_bf16(a, b0, acc[0][ks & 1], 0, 0, 0);
        acc[1][ks & 1] = __builtin_amdgcn_mfma_f32_16x16x32_bf16(a, b1, acc[1][ks & 1], 0, 0, 0);
      }
      __syncthreads();
#pragma unroll
      for (int nfi = 0; nfi < 2; ++nfi) {
        int col = ((w & 1) * 2 + nfi) * 16 + l15;
#pragma unroll
        for (int r = 0; r < 4; ++r) {
          int lrow = lq * 4 + r;
          glf[(g * 16 + lrow) * 64 + ((col + (lrow >> 2) * 8) & 63)] =
              acc[nfi][0][r] + acc[nfi][1][r];
        }
      }
    } else {
      f32x4 acca = {}, accb = {};
#pragma unroll 4
      for (int ks = 0; ks < NKS; ++ks) {
        bf16x8 a = *reinterpret_cast<const bf16x8*>(ap + ((ks * 64 + lq * 16) ^ swz));
        bf16x8 b0 = *reinterpret_cast<const bf16x8*>(bb0 + ks * 512);
        if (ks & 1) accb = __builtin_amdgcn_mfma_f32_16x16x32_bf16(a, b0, accb, 0, 0, 0);
        else        acca = __builtin_amdgcn_mfma_f32_16x16x32_bf16(a, b0, acca, 0, 0, 0);
      }
      __syncthreads();
      {
        int col = (w & 1) * 16 + l15;
#pragma unroll
        for (int r = 0; r < 4; ++r) {
          int lrow = lq * 4 + r;
          glf[(g * 16 + lrow) * 32 + ((col + (lrow >> 2) * 8) & 31)] = acca[r] + accb[r];
        }
      }
    }
    __syncthreads();
    // ---- elementwise: c in regs, parity-packed dual store (no drain, no flag) ----
    if (ew) {
      float2 vi = *reinterpret_cast<float2*>(&glf[(0 * 16 + erow) * NCOL + ((ecp + esh) & (NCOL - 1))]);
      float2 vf = *reinterpret_cast<float2*>(&glf[(1 * 16 + erow) * NCOL + ((ecp + esh) & (NCOL - 1))]);
      float2 vo = *reinterpret_cast<float2*>(&glf[(2 * 16 + erow) * NCOL + ((ecp + esh) & (NCOL - 1))]);
      float2 vg = *reinterpret_cast<float2*>(&glf[(3 * 16 + erow) * NCOL + ((ecp + esh) & (NCOL - 1))]);
      float bi0, bi1, bf0, bf1, bo0, bo1, bg0, bg1;
      if (L == 0) {
        bi0 = tb[0].x; bi1 = tb[0].y; bf0 = tb[1].x; bf1 = tb[1].y;
        bo0 = tb[2].x; bo1 = tb[2].y; bg0 = tb[3].x; bg1 = tb[3].y;
      } else {
        bi0 = breg[0].x; bi1 = breg[0].y; bf0 = breg[1].x; bf1 = breg[1].y;
        bo0 = breg[2].x; bo1 = breg[2].y; bg0 = breg[3].x; bg1 = breg[3].y;
      }
      float cv0 = sigm(vf.x + bf0) * c0 + sigm(vi.x + bi0) * tanhf(vg.x + bg0);
      float cv1 = sigm(vf.y + bf1) * c1 + sigm(vi.y + bi1) * tanhf(vg.y + bg1);
      c0 = cv0; c1 = cv1;
      float h0v = sigm(vo.x + bo0) * tanhf(cv0);
      float h1v = sigm(vo.y + bo1) * tanhf(cv1);
      u32 po = (u32)((t >> 4) & 1);
      u32 pk0 = ((u32)(u16)f2bf(h0v) & ~1u) | po;
      u32 pk1 = ((u32)(u16)f2bf(h1v) & ~1u) | po;
      // note: this role packs 2 cols per thread -> 4B payload; widen to 8B by pairing
      // adjacent threads is unnecessary: store both cols in one dword.
      u32 pk = pk0 | (pk1 << 16);
      size_t eo = (size_t)(t & 15) * 65536 + (size_t)(m0 + erow) * 512 + cs * NCOL + ecp;
      u16* rL = (L == 0) ? h0loc : h1loc;
      u16* rM = (L == 0) ? h0mall : h1mall;
      asm volatile("global_store_dword %0, %1, off"
                   :: "v"((u64)(uintptr_t)(rL + eo)), "v"(pk) : "memory");
      asm volatile("global_store_dword %0, %1, off sc0 sc1"
                   :: "v"((u64)(uintptr_t)(rM + eo)), "v"(pk) : "memory");
    }
    __syncthreads();
  }
  vm_drain();
}

// ---------------- projection role ----------------
__device__ void proj_role(char* smem, int bg, int tid,
    const u16* __restrict__ h1loc, const u16* __restrict__ h1mall, u32* __restrict__ FP,
    const short* __restrict__ pWswz, const float* __restrict__ lng,
    const float* __restrict__ lnb, const float* __restrict__ pb,
    float* __restrict__ out)
{
  const int w = tid >> 6, lane = tid & 63, l15 = lane & 15, lq = lane >> 4;
  const int m0 = bg * 16;
  const short* bp0 = pWswz + (size_t)(w * 2) * 8192 + lane * 8;
  const short* bp1 = bp0 + 8192;
  const int swzrow = (l15 & 7) << 4;
  float pb0 = pb[(w * 2) * 16 + l15], pb1 = pb[(w * 2 + 1) * 16 + l15];

  for (int t = 0; t < 1024; ++t) {
    {
      const u32 pm = ((t >> 4) & 1) ? 0x00010001u : 0u;
      const size_t off = (size_t)(t & 15) * 65536 + (size_t)m0 * 512;
      const u16* sL = h1loc + off;
      const u16* sM = h1mall + off;
      u32x4 v[2];
      int rr_[2], sg_[2];
#pragma unroll
      for (int k = 0; k < 2; ++k) {
        int gidx = tid + k * 512;
        rr_[k] = gidx >> 6; sg_[k] = gidx & 63;
        v[k] = ld128_loc(sL + rr_[k] * 512 + sg_[k] * 8);
      }
      int pend = 3, rnd = 0;
      while (pend) {
        vm_drain();
        int np = 0;
        const bool useM = (rnd >= 4) && (rnd & 1);
#pragma unroll
        for (int k = 0; k < 2; ++k) if (pend & (1 << k)) {
          if (par_ok(v[k], pm))
            *reinterpret_cast<u32x4*>(smem + rr_[k] * 1024 + sg_[k] * 16) = v[k];
          else {
            np |= 1 << k;
            v[k] = useM ? ld128_sys(sM + rr_[k] * 512 + sg_[k] * 8)
                        : ld128_loc(sL + rr_[k] * 512 + sg_[k] * 8);
          }
        }
        pend = np; ++rnd;
      }
    }
    __syncthreads();
    if (tid == 0) st_flag(&FP[(192 + bg) * 4], (u32)(t + 1));
    {
      int row = tid >> 5, j = tid & 31;
      const u16* hr = reinterpret_cast<const u16*>(smem) + row * 512;
      float s1 = 0.f, s2 = 0.f;
#pragma unroll
      for (int kk = 0; kk < 16; ++kk) {
        float v = bf2f(hr[j + kk * 32]);
        s1 += v; s2 += v * v;
      }
#pragma unroll
      for (int d = 1; d < 32; d <<= 1) { s1 += __shfl_xor(s1, d, 32); s2 += __shfl_xor(s2, d, 32); }
      float mu = s1 * (1.f / 512.f);
      float rs = rsqrtf(s2 * (1.f / 512.f) - mu * mu + 1e-5f);
      char* zn = smem + 16384;
#pragma unroll
      for (int kk = 0; kk < 16; ++kk) {
        int kcol = j + kk * 32;
        float v = bf2f(hr[kcol]);
        float nv = (v - mu) * rs * lng[kcol] + lnb[kcol];
        *reinterpret_cast<short*>(zn + row * 1024 + ((kcol * 2) ^ ((row & 7) << 4))) = f2bf(nv);
      }
    }
    __syncthreads();
    const char* ap = smem + 16384 + (size_t)l15 * 1024;
    f32x4 acc[2][2] = {};
#pragma unroll 4
    for (int ks = 0; ks < 16; ++ks) {
      bf16x8 a = *reinterpret_cast<const bf16x8*>(ap + ((ks * 64 + lq * 16) ^ swzrow));
      bf16x8 b0 = *reinterpret_cast<const bf16x8*>(bp0 + ks * 512);
      bf16x8 b1 = *reinterpret_cast<const bf16x8*>(bp1 + ks * 512);
      acc[0][ks & 1] = __builtin_amdgcn_mfma_f32_16x16x32_bf16(a, b0, acc[0][ks & 1], 0, 0, 0);
      acc[1][ks & 1] = __builtin_amdgcn_mfma_f32_16x16x32_bf16(a, b1, acc[1][ks & 1], 0, 0, 0);
    }
#pragma unroll
    for (int nfi = 0; nfi < 2; ++nfi) {
      int vcol = (w * 2 + nfi) * 16 + l15;
      float pbv = nfi ? pb1 : pb0;
#pragma unroll
      for (int r = 0; r < 4; ++r) {
        float vv = acc[nfi][0][r] + acc[nfi][1][r] + pbv;
        out[(size_t)(m0 + lq * 4 + r) * 262144 + (size_t)t * 256 + vcol] = vv;
      }
    }
    __syncthreads();
  }
}

// Grid: 200 blocks; cluster = bid & 7 (round-robin XCD heuristic), slot = bid >> 3.
// Each cluster hosts one bg's full pipeline: slot 0..7 = L0 cs, 8..23 = L1 cs, 24 = proj.
__global__ __launch_bounds__(512, 1) void persist_kernel(
    const short* __restrict__ W0h, const short* __restrict__ W1,
    const float* __restrict__ table, const float* __restrict__ bias1,
    const int* __restrict__ xT,
    u16* __restrict__ h0loc, u16* __restrict__ h1loc,
    u16* __restrict__ h0mall, u16* __restrict__ h1mall, u32* __restrict__ flags,
    const short* __restrict__ pWswz, const float* __restrict__ lng,
    const float* __restrict__ lnb, const float* __restrict__ pb, float* __restrict__ out)
{
  __shared__ __align__(16) char smem[49408];
  const int bid = blockIdx.x, tid = threadIdx.x;
  const int bg = bid & 7, slot = bid >> 3;
  if (slot < 8) {
    lstm_role<0>(smem, bg, slot, tid, W0h, table, nullptr, xT,
                 h0loc, h1loc, h0mall, h1mall, flags);
  } else if (slot < 24) {
    lstm_role<1>(smem, bg, slot - 8, tid, W1, nullptr, bias1, xT,
                 h0loc, h1loc, h0mall, h1mall, flags);
  } else {
    proj_role(smem, bg, tid, h1loc, h1mall, flags, pWswz, lng, lnb, pb, out);
  }
}

extern "C" void kernel_launch(void* const* d_in, const int* in_sizes, int n_in,
                              void* d_out, int out_size, void* d_ws, size_t ws_size,
                              hipStream_t stream) {
  const int*   x    = (const int*)d_in[0];
  const float* emb  = (const float*)d_in[1];
  const float* W    = (const float*)d_in[2];
  const float* bias = (const float*)d_in[3];
  const float* lng  = (const float*)d_in[4];
  const float* lnb  = (const float*)d_in[5];
  const float* pW   = (const float*)d_in[6];
  const float* pb   = (const float*)d_in[7];
  float* out = (float*)d_out;

  char* ws = (char*)d_ws;
  short* W0h   = (short*)(ws + 0);           // 2 MB
  short* W1sw  = (short*)(ws + 2097152);     // 4 MB
  short* pWsw  = (short*)(ws + 6291456);     // 256 KB -> ends 6553600
  float* table = (float*)(ws + 6553600);     // 2 MB   -> ends 8650752
  int*   xT    = (int*)(ws + 8650752);       // 512 KB -> ends 9175040
  u32*   flags = (u32*)(ws + 9175040);       // 4 KB (padded to 9437184)
  u16*   h0loc = (u16*)(ws + 9437184);       // 2 MB: 16 x [128][512] bf16 (parity LSB)
  u16*   h1loc = (u16*)(ws + 11534336);      // 2 MB
  u16*   h0mall= (u16*)(ws + 13631488);      // 2 MB
  u16*   h1mall= (u16*)(ws + 15728640);      // 2 MB -> ends 17825792
  short* W0x   = (short*)(ws + 13631488);    // temp alias over h0mall (table build only)

  swz_generic<<<dim3(512), dim3(256), 0, stream>>>(W, W0h, 1024, 512, 16, 131072);
  swz_generic<<<dim3(1024), dim3(256), 0, stream>>>(W + 2048 * 1024, W1sw, 1024, 0, 32, 262144);
  swz_generic<<<dim3(64), dim3(256), 0, stream>>>(pW, pWsw, 512, 0, 16, 16384);
  xpose_kernel<<<dim3(512), dim3(256), 0, stream>>>(x, xT);
  swz_generic<<<dim3(512), dim3(256), 0, stream>>>(W, W0x, 1024, 0, 16, 131072);
  table_kernel<<<dim3(4, 16), dim3(512), 0, stream>>>(emb, W0x, bias, table);
  hipMemsetAsync(ws + 9175040, 0, 4096, stream);          // prog flags
  hipMemsetAsync(ws + 9437184, 0x01, 8388608, stream);    // all 4 rings: parity-reject init

  persist_kernel<<<dim3(200), dim3(512), 0, stream>>>(
      W0h, W1sw, table, bias + 2048, xT, h0loc, h1loc, h0mall, h1mall, flags,
      pWsw, lng, lnb, pb, out);
}